// Round 1
// baseline (561.625 us; speedup 1.0000x reference)
//
#include <hip/hip_runtime.h>
#include <math.h>

// Sum-product network over a binary tree. B=256 batch, D=1024 leaves, K=128.
// Per level: product (add adjacent children's log-probs) then log-space mixture
//   out[b,i] = m[b] + log( sum_j exp(w[i,j]) * exp(prod[b,j]-m[b]) ) - log( sum_j exp(w[i,j]) )
// which equals logsumexp_j( log_softmax(w)[i,j] + prod[b,j] ).

#define BB 256
#define DD 1024
#define KK 128
#define BT 128   // batch rows per workgroup
#define NT 256   // threads per workgroup

#define HALF_LOG_2PI 0.9189385332046727f

// LDS layout (floats):
//   Wl    [128*128]  exp(weights) row-major, quad-swizzled columns
//   El    [128*128]  exp(prod - m), quad-swizzled columns
//   logrs [128]      log of row sums of exp(W)
//   mrow  [128]      per-b row max
//   red   [256]      reduction scratch
#define SM_FLOATS (16384 + 16384 + 128 + 128 + 256)

template <bool LEAF>
__global__ __launch_bounds__(NT, 1) void spn_level(
    const float* __restrict__ x, const float* __restrict__ mu,
    const float* __restrict__ ls, const float* __restrict__ yprev,
    const float* __restrict__ weights, float* __restrict__ yout,
    int d, int woff)
{
    extern __shared__ float smem[];
    float* Wl    = smem;
    float* El    = smem + 16384;
    float* logrs = smem + 32768;
    float* mrow  = smem + 32896;
    float* red   = smem + 33024;

    const int n     = blockIdx.x;
    const int btile = blockIdx.y;
    const int t     = threadIdx.x;

    // ---------------- Phase W: stage exp(weights[woff+n]) + row sums --------
    {
        const int i = t >> 1;          // row 0..127
        const int h = t & 1;           // half of the row
        const float* wg = weights + (((size_t)(woff + n)) << 14) + (i << 7) + (h << 6);
        const int sw = ((i >> 2) & 7) << 2;   // quad swizzle for this row
        float ps = 0.f;
        #pragma unroll
        for (int q = 0; q < 16; ++q) {
            float4 v = *(const float4*)(wg + 4 * q);
            v.x = __expf(v.x); v.y = __expf(v.y);
            v.z = __expf(v.z); v.w = __expf(v.w);
            ps += (v.x + v.y) + (v.z + v.w);
            const int j0 = (h << 6) + 4 * q;
            *(float4*)&Wl[(i << 7) + (j0 ^ sw)] = v;
        }
        red[t] = ps;
    }
    __syncthreads();
    if (t < KK) logrs[t] = __logf(red[2 * t] + red[2 * t + 1]);
    __syncthreads();   // red is reused below

    // ---------------- Phase E: product of children, store to LDS, row max ---
    {
        const int bl = t & 127;        // local batch row
        const int h  = t >> 7;         // half of the row
        const int b  = btile * BT + bl;
        const int se = ((bl >> 3) & 3) << 2;
        float lmax = -3.0e38f;
        float xa = 0.f, xb = 0.f;
        if (LEAF) {
            xa = x[(size_t)b * DD + 2 * n];
            xb = x[(size_t)b * DD + 2 * n + 1];
        }
        const float* ra = LEAF ? nullptr
                               : yprev + ((size_t)b * (2 * d) + 2 * n) * KK;
        #pragma unroll 4
        for (int q = 0; q < 16; ++q) {
            const int j0 = (h << 6) + 4 * q;
            float4 p;
            if (LEAF) {
                const float4 ma = *(const float4*)(mu + (size_t)(2 * n) * KK + j0);
                const float4 mb = *(const float4*)(mu + (size_t)(2 * n + 1) * KK + j0);
                const float4 la = *(const float4*)(ls + (size_t)(2 * n) * KK + j0);
                const float4 lb = *(const float4*)(ls + (size_t)(2 * n + 1) * KK + j0);
                float za, zb2, ya, yb;
                za = (xa - ma.x) * __expf(-la.x); ya = -0.5f * za * za - la.x - HALF_LOG_2PI;
                zb2 = (xb - mb.x) * __expf(-lb.x); yb = -0.5f * zb2 * zb2 - lb.x - HALF_LOG_2PI;
                p.x = ya + yb;
                za = (xa - ma.y) * __expf(-la.y); ya = -0.5f * za * za - la.y - HALF_LOG_2PI;
                zb2 = (xb - mb.y) * __expf(-lb.y); yb = -0.5f * zb2 * zb2 - lb.y - HALF_LOG_2PI;
                p.y = ya + yb;
                za = (xa - ma.z) * __expf(-la.z); ya = -0.5f * za * za - la.z - HALF_LOG_2PI;
                zb2 = (xb - mb.z) * __expf(-lb.z); yb = -0.5f * zb2 * zb2 - lb.z - HALF_LOG_2PI;
                p.z = ya + yb;
                za = (xa - ma.w) * __expf(-la.w); ya = -0.5f * za * za - la.w - HALF_LOG_2PI;
                zb2 = (xb - mb.w) * __expf(-lb.w); yb = -0.5f * zb2 * zb2 - lb.w - HALF_LOG_2PI;
                p.w = ya + yb;
            } else {
                const float4 a  = *(const float4*)(ra + j0);
                const float4 b2 = *(const float4*)(ra + KK + j0);
                p.x = a.x + b2.x; p.y = a.y + b2.y;
                p.z = a.z + b2.z; p.w = a.w + b2.w;
            }
            *(float4*)&El[(bl << 7) + (j0 ^ se)] = p;
            lmax = fmaxf(lmax, fmaxf(fmaxf(p.x, p.y), fmaxf(p.z, p.w)));
        }
        red[t] = lmax;
    }
    __syncthreads();
    if (t < BT) mrow[t] = fmaxf(red[t], red[t + 128]);
    __syncthreads();

    // ---------------- exp pass: E = exp(prod - m), in place (swizzle-agnostic)
    {
        const int bl = t & 127;
        const int h  = t >> 7;
        const float m = mrow[bl];
        float* er = El + (bl << 7) + (h << 6);
        #pragma unroll
        for (int q = 0; q < 16; ++q) {
            float4 v = *(float4*)(er + 4 * q);
            v.x = __expf(v.x - m); v.y = __expf(v.y - m);
            v.z = __expf(v.z - m); v.w = __expf(v.w - m);
            *(float4*)(er + 4 * q) = v;
        }
    }
    __syncthreads();

    // ---------------- GEMM: s[b,i] = sum_j E[b,j] * Wexp[i,j] ---------------
    // thread tile: 8 b-rows x 8 i-cols (i as two quads: 4*ti..+3 and 64+4*ti..+3)
    const int ti = t & 15;
    const int tb = t >> 4;
    const int se = (tb & 3) << 2;
    const int sw = (ti & 7) << 2;
    const float* eb = El + ((tb * 8) << 7);
    const float* w0 = Wl + ((ti * 4) << 7);
    const float* w1 = Wl + ((64 + ti * 4) << 7);

    float acc[8][8];
    #pragma unroll
    for (int r = 0; r < 8; ++r)
        #pragma unroll
        for (int c = 0; c < 8; ++c) acc[r][c] = 0.f;

    #pragma unroll 2
    for (int s = 0; s < 32; ++s) {
        const int jo = 4 * s;
        float4 ev[8], wv[8];
        #pragma unroll
        for (int r = 0; r < 8; ++r) ev[r] = *(const float4*)(eb + (r << 7) + (jo ^ se));
        #pragma unroll
        for (int c = 0; c < 4; ++c) wv[c]     = *(const float4*)(w0 + (c << 7) + (jo ^ sw));
        #pragma unroll
        for (int c = 0; c < 4; ++c) wv[4 + c] = *(const float4*)(w1 + (c << 7) + (jo ^ sw));
        #pragma unroll
        for (int r = 0; r < 8; ++r)
            #pragma unroll
            for (int c = 0; c < 8; ++c)
                acc[r][c] += ev[r].x * wv[c].x + ev[r].y * wv[c].y +
                             ev[r].z * wv[c].z + ev[r].w * wv[c].w;
    }

    // ---------------- epilogue: out = m[b] + log(s) - log(rowsum) -----------
    {
        const int brow0 = btile * BT + tb * 8;
        float lr0[4], lr1[4];
        #pragma unroll
        for (int c = 0; c < 4; ++c) { lr0[c] = logrs[4 * ti + c]; lr1[c] = logrs[64 + 4 * ti + c]; }
        #pragma unroll
        for (int r = 0; r < 8; ++r) {
            const float m = mrow[tb * 8 + r];
            float4 o0, o1;
            o0.x = m + __logf(acc[r][0]) - lr0[0];
            o0.y = m + __logf(acc[r][1]) - lr0[1];
            o0.z = m + __logf(acc[r][2]) - lr0[2];
            o0.w = m + __logf(acc[r][3]) - lr0[3];
            o1.x = m + __logf(acc[r][4]) - lr1[0];
            o1.y = m + __logf(acc[r][5]) - lr1[1];
            o1.z = m + __logf(acc[r][6]) - lr1[2];
            o1.w = m + __logf(acc[r][7]) - lr1[3];
            const size_t base = ((size_t)(brow0 + r) * d + n) * KK;
            *(float4*)&yout[base + 4 * ti]      = o0;
            *(float4*)&yout[base + 64 + 4 * ti] = o1;
        }
    }
}

extern "C" void kernel_launch(void* const* d_in, const int* in_sizes, int n_in,
                              void* d_out, int out_size, void* d_ws, size_t ws_size,
                              hipStream_t stream) {
    const float* x  = (const float*)d_in[0];
    const float* mu = (const float*)d_in[1];
    const float* ls = (const float*)d_in[2];
    const float* w  = (const float*)d_in[3];
    float* out  = (float*)d_out;
    float* buf0 = (float*)d_ws;                       // [256][512][128] f32 = 67 MB
    float* buf1 = buf0 + (size_t)BB * 512 * KK;       // [256][256][128] f32 = 34 MB

    const size_t shmem = SM_FLOATS * sizeof(float);   // ~130 KB dynamic LDS
    (void)hipFuncSetAttribute((const void*)spn_level<true>,
                              hipFuncAttributeMaxDynamicSharedMemorySize, (int)shmem);
    (void)hipFuncSetAttribute((const void*)spn_level<false>,
                              hipFuncAttributeMaxDynamicSharedMemorySize, (int)shmem);

    // Level 1 (d=512): leaves fused, weights[0:512], out -> buf0
    spn_level<true><<<dim3(512, 2), dim3(NT), shmem, stream>>>(
        x, mu, ls, nullptr, w, buf0, 512, 0);

    // Levels d = 256 .. 1, ping-pong buffers, last writes d_out
    const float* src = buf0;
    float* dst = buf1;
    int woff = 512;
    for (int d = 256; d >= 1; d >>= 1) {
        float* o = (d == 1) ? out : dst;
        spn_level<false><<<dim3(d, 2), dim3(NT), shmem, stream>>>(
            nullptr, nullptr, nullptr, src, w, o, d, woff);
        woff += d;
        dst = (float*)src;
        src = o;
    }
}

// Round 2
// 268.380 us; speedup vs baseline: 2.0927x; 2.0927x over previous
//
#include <hip/hip_runtime.h>
#include <math.h>

// Sum-product network over a binary tree. B=256, D=1024 leaves, K=128.
// Per level: product (add adjacent children's log-probs) then log-space mixture:
//   out[b,i] = m[b] + log( sum_j exp(w[i,j]) * exp(p[b,j]-m[b]) ) - log( sum_j exp(w[i,j]) )
// GEMM part done with MFMA 16x16x32 bf16 in split precision (hi+lo), error ~1e-4.

#define DD 1024
#define KK 128
#define NT 256
#define HALF_LOG_2PI 0.9189385332046727f

typedef __attribute__((ext_vector_type(8))) short bf16x8;
typedef __attribute__((ext_vector_type(4))) float f32x4;

__device__ __forceinline__ unsigned short bf16_rn(float f) {
    unsigned u = __builtin_bit_cast(unsigned, f);
    u += 0x7fffu + ((u >> 16) & 1u);
    return (unsigned short)(u >> 16);
}
__device__ __forceinline__ float bf16f(unsigned short h) {
    unsigned u = ((unsigned)h) << 16;
    return __builtin_bit_cast(float, u);
}

// LDS byte layout (max over variants):
//   Whi [128][128] ushort : 32768
//   Wlo [128][128] ushort : 32768
//   Ehi [BT][128] ushort  : BT*256
//   Elo [BT][128] ushort  : BT*256
//   logrs f32[128], mrow f32[BT], redW f32[256], redE f32[256], musig f32[768]
template <int BT, bool LEAF>
__global__ __launch_bounds__(NT, 1) void spn_level(
    const float* __restrict__ x, const float* __restrict__ mu,
    const float* __restrict__ ls, const float* __restrict__ yprev,
    const float* __restrict__ weights, float* __restrict__ yout,
    int d, int woff)
{
    constexpr int JPT = NT / BT;    // threads per b-row
    constexpr int JW  = KK / JPT;   // j elems per thread

    extern __shared__ char smem[];
    unsigned short* Whi = (unsigned short*)smem;            // [128][128]
    unsigned short* Wlo = Whi + 128 * 128;
    unsigned short* Ehi = Wlo + 128 * 128;                  // [BT][128]
    unsigned short* Elo = Ehi + BT * 128;
    float* logrs = (float*)(Elo + BT * 128);                // [128]
    float* mrow  = logrs + 128;                             // [BT]
    float* redW  = mrow + BT;                               // [256]
    float* redE  = redW + NT;                               // [256]
    float* musig = redE + NT;                               // [768] leaf constants

    const int n     = blockIdx.x;
    const int btile = blockIdx.y;
    const int t     = threadIdx.x;

    // ---------------- Phase 1: leaf constants + W stage (exp, split, rowsum) ----
    if (LEAF) {
        const int c = t >> 7, j = t & 127;
        const float lsv = ls[(size_t)(2 * n + c) * KK + j];
        musig[c * 128 + j]       = __expf(-lsv);
        musig[256 + c * 128 + j] = -lsv - HALF_LOG_2PI;
        musig[512 + c * 128 + j] = mu[(size_t)(2 * n + c) * KK + j];
    }
    {
        const int i = t >> 1;          // W row 0..127
        const int h = t & 1;
        const float* wg = weights + (((size_t)(woff + n)) << 14) + (i << 7) + (h << 6);
        const int sw = (i & 7) << 3;   // ushort-unit swizzle
        unsigned short* wh = Whi + i * 128;
        unsigned short* wl = Wlo + i * 128;
        float ps = 0.f;
        #pragma unroll
        for (int c = 0; c < 8; ++c) {
            float4 v0 = *(const float4*)(wg + 8 * c);
            float4 v1 = *(const float4*)(wg + 8 * c + 4);
            float e[8] = {__expf(v0.x), __expf(v0.y), __expf(v0.z), __expf(v0.w),
                          __expf(v1.x), __expf(v1.y), __expf(v1.z), __expf(v1.w)};
            bf16x8 hv, lv;
            #pragma unroll
            for (int q = 0; q < 8; ++q) {
                ps += e[q];
                const unsigned short hb = bf16_rn(e[q]);
                hv[q] = (short)hb;
                lv[q] = (short)bf16_rn(e[q] - bf16f(hb));
            }
            const int j0 = (h << 6) + 8 * c;
            *(bf16x8*)&wh[j0 ^ sw] = hv;
            *(bf16x8*)&wl[j0 ^ sw] = lv;
        }
        redW[t] = ps;
    }
    __syncthreads();   // bar0: W planes, redW, musig ready

    // ---------------- Phase 2: log of W row sums + E products ------------------
    if (t < 128) logrs[t] = __logf(redW[2 * t] + redW[2 * t + 1]);

    const int bl = t & (BT - 1);
    const int jh = t / BT;
    const int b  = btile * BT + bl;
    float p[JW];
    float lmax = -3.0e38f;
    if (LEAF) {
        const float xa = x[(size_t)b * DD + 2 * n];
        const float xb = x[(size_t)b * DD + 2 * n + 1];
        const float* isga = musig;        const float* isgb = musig + 128;
        const float* cta  = musig + 256;  const float* ctb  = musig + 384;
        const float* mva  = musig + 512;  const float* mvb  = musig + 640;
        #pragma unroll
        for (int c = 0; c < JW / 4; ++c) {
            const int j = jh * JW + 4 * c;
            const float4 ia = *(const float4*)(isga + j);
            const float4 ib = *(const float4*)(isgb + j);
            const float4 ca = *(const float4*)(cta + j);
            const float4 cb = *(const float4*)(ctb + j);
            const float4 ma = *(const float4*)(mva + j);
            const float4 mb = *(const float4*)(mvb + j);
            float za, zb, v;
            za = (xa - ma.x) * ia.x; zb = (xb - mb.x) * ib.x;
            v = fmaf(-0.5f * za, za, ca.x) + fmaf(-0.5f * zb, zb, cb.x);
            p[4 * c + 0] = v; lmax = fmaxf(lmax, v);
            za = (xa - ma.y) * ia.y; zb = (xb - mb.y) * ib.y;
            v = fmaf(-0.5f * za, za, ca.y) + fmaf(-0.5f * zb, zb, cb.y);
            p[4 * c + 1] = v; lmax = fmaxf(lmax, v);
            za = (xa - ma.z) * ia.z; zb = (xb - mb.z) * ib.z;
            v = fmaf(-0.5f * za, za, ca.z) + fmaf(-0.5f * zb, zb, cb.z);
            p[4 * c + 2] = v; lmax = fmaxf(lmax, v);
            za = (xa - ma.w) * ia.w; zb = (xb - mb.w) * ib.w;
            v = fmaf(-0.5f * za, za, ca.w) + fmaf(-0.5f * zb, zb, cb.w);
            p[4 * c + 3] = v; lmax = fmaxf(lmax, v);
        }
    } else {
        const float* ra = yprev + ((size_t)b * (2 * d) + 2 * n) * KK + jh * JW;
        const float* rb = ra + KK;
        #pragma unroll
        for (int c = 0; c < JW / 4; ++c) {
            const float4 a4 = *(const float4*)(ra + 4 * c);
            const float4 b4 = *(const float4*)(rb + 4 * c);
            const float p0 = a4.x + b4.x, p1 = a4.y + b4.y;
            const float p2 = a4.z + b4.z, p3 = a4.w + b4.w;
            p[4 * c + 0] = p0; p[4 * c + 1] = p1;
            p[4 * c + 2] = p2; p[4 * c + 3] = p3;
            lmax = fmaxf(lmax, fmaxf(fmaxf(p0, p1), fmaxf(p2, p3)));
        }
    }
    redE[t] = lmax;
    __syncthreads();   // bar1

    // ---------------- Phase 3: row max + exp/split/store E ---------------------
    if (t < BT) {
        float m = redE[t];
        #pragma unroll
        for (int q = 1; q < JPT; ++q) m = fmaxf(m, redE[t + BT * q]);
        mrow[t] = m;
    }
    float mx = redE[bl];
    #pragma unroll
    for (int q = 1; q < JPT; ++q) mx = fmaxf(mx, redE[bl + BT * q]);
    {
        const int sw = (bl & 7) << 3;
        unsigned short* eh = Ehi + bl * 128;
        unsigned short* el = Elo + bl * 128;
        #pragma unroll
        for (int c = 0; c < JW / 8; ++c) {
            bf16x8 hv, lv;
            #pragma unroll
            for (int q = 0; q < 8; ++q) {
                const float ev = __expf(p[8 * c + q] - mx);
                const unsigned short hb = bf16_rn(ev);
                hv[q] = (short)hb;
                lv[q] = (short)bf16_rn(ev - bf16f(hb));
            }
            const int j0 = jh * JW + 8 * c;
            *(bf16x8*)&eh[j0 ^ sw] = hv;
            *(bf16x8*)&el[j0 ^ sw] = lv;
        }
    }
    __syncthreads();   // bar2: E planes, mrow, logrs ready

    // ---------------- Phase 4: MFMA GEMM + log epilogue ------------------------
    // s[b,i] = sum_j E[b,j] * Wexp[i,j]   (B^T pattern: both frags row-contiguous)
    const int w  = t >> 6;
    const int ln = t & 63;
    const int lr = ln & 15;
    const int lk = ln >> 4;
    constexpr int NWB = (BT == 128) ? 4 : 1;
    const int bt0 = (BT == 128) ? ((w >> 1) * 4) : (w & 1);
    const int it0 = (BT == 128) ? ((w & 1) * 4) : ((w >> 1) * 4);

    f32x4 acc[NWB][4];
    #pragma unroll
    for (int bi = 0; bi < NWB; ++bi)
        #pragma unroll
        for (int ci = 0; ci < 4; ++ci) acc[bi][ci] = (f32x4){0.f, 0.f, 0.f, 0.f};

    const int kb = lk * 8;
    #pragma unroll
    for (int ks = 0; ks < 4; ++ks) {
        const int jo = ks * 32 + kb;
        bf16x8 ah[NWB], al[NWB];
        #pragma unroll
        for (int bi = 0; bi < NWB; ++bi) {
            const int r = (bt0 + bi) * 16 + lr;
            const int idx = r * 128 + (jo ^ ((r & 7) << 3));
            ah[bi] = *(bf16x8*)&Ehi[idx];
            al[bi] = *(bf16x8*)&Elo[idx];
        }
        #pragma unroll
        for (int ci = 0; ci < 4; ++ci) {
            const int r = (it0 + ci) * 16 + lr;
            const int idx = r * 128 + (jo ^ ((r & 7) << 3));
            const bf16x8 bh = *(bf16x8*)&Whi[idx];
            const bf16x8 blo = *(bf16x8*)&Wlo[idx];
            #pragma unroll
            for (int bi = 0; bi < NWB; ++bi) {
                acc[bi][ci] = __builtin_amdgcn_mfma_f32_16x16x32_bf16(ah[bi], bh,  acc[bi][ci], 0, 0, 0);
                acc[bi][ci] = __builtin_amdgcn_mfma_f32_16x16x32_bf16(ah[bi], blo, acc[bi][ci], 0, 0, 0);
                acc[bi][ci] = __builtin_amdgcn_mfma_f32_16x16x32_bf16(al[bi], bh,  acc[bi][ci], 0, 0, 0);
            }
        }
    }

    #pragma unroll
    for (int bi = 0; bi < NWB; ++bi) {
        const int brl = (bt0 + bi) * 16 + lk * 4;   // local b-row base (C/D: row=(l>>4)*4+reg)
        #pragma unroll
        for (int ci = 0; ci < 4; ++ci) {
            const int ic = (it0 + ci) * 16 + lr;    // C/D: col=lane&15
            const float lrs = logrs[ic];
            const f32x4 a = acc[bi][ci];
            #pragma unroll
            for (int r = 0; r < 4; ++r) {
                const float m = mrow[brl + r];
                const size_t off = ((size_t)(btile * BT + brl + r) * d + n) * KK + ic;
                yout[off] = m + __logf(a[r]) - lrs;
            }
        }
    }
}

extern "C" void kernel_launch(void* const* d_in, const int* in_sizes, int n_in,
                              void* d_out, int out_size, void* d_ws, size_t ws_size,
                              hipStream_t stream) {
    const float* x  = (const float*)d_in[0];
    const float* mu = (const float*)d_in[1];
    const float* ls = (const float*)d_in[2];
    const float* w  = (const float*)d_in[3];
    float* out  = (float*)d_out;
    float* buf0 = (float*)d_ws;                       // [256][512][128] f32 = 67 MB
    float* buf1 = buf0 + (size_t)256 * 512 * KK;      // [256][256][128] f32 = 34 MB

    // dynamic LDS sizes
    const int sh128 = 65536 + 128 * 512 + 512 + 512 + 1024 + 1024 + 3072;  // 137216
    const int sh32  = 65536 +  32 * 512 + 512 + 128 + 1024 + 1024 + 3072;  //  87680

    (void)hipFuncSetAttribute((const void*)spn_level<128, true>,
                              hipFuncAttributeMaxDynamicSharedMemorySize, sh128);
    (void)hipFuncSetAttribute((const void*)spn_level<128, false>,
                              hipFuncAttributeMaxDynamicSharedMemorySize, sh128);
    (void)hipFuncSetAttribute((const void*)spn_level<32, false>,
                              hipFuncAttributeMaxDynamicSharedMemorySize, sh32);

    // Level 1 (d=512): leaves fused, weights[0:512], out -> buf0
    spn_level<128, true><<<dim3(512, 2), dim3(NT), sh128, stream>>>(
        x, mu, ls, nullptr, w, buf0, 512, 0);

    const float* src = buf0;
    float* other = buf1;
    int woff = 512;
    for (int d = 256; d >= 1; d >>= 1) {
        float* o = (d == 1) ? out : other;
        if (d >= 64) {
            spn_level<128, false><<<dim3(d, 2), dim3(NT), sh128, stream>>>(
                nullptr, nullptr, nullptr, src, w, o, d, woff);
        } else {
            spn_level<32, false><<<dim3(d, 8), dim3(NT), sh32, stream>>>(
                nullptr, nullptr, nullptr, src, w, o, d, woff);
        }
        woff += d;
        other = (float*)src;
        src = o;
    }
}